// Round 10
// baseline (5043.090 us; speedup 1.0000x reference)
//
#include <hip/hip_runtime.h>
#include <cstdint>

// B=32, S=1024, D=1024 ContractiveSequenceMixer.
// R10: R5-EXACT recurrence core (best measured: 3240us) with exactly two
// bounded changes, as an A/B discriminating L3-contention vs pure latency:
//  (1) packed flags: each consumer wave's 8 producer flags live in ONE
//      contiguous 32B region (one fabric segment per poll iteration,
//      vs 8 separate 64B-spaced lines).
//  (2) G/P prefetch moved AFTER the publish (producer's vmcnt(0) ack can
//      never wait on an HBM prefetch).
// Everything else identical to R5 (ack-then-flag, parity h, wave0 epilogue).

#define BATCH 32
#define SEQ   1024
#define DIM   1024
static const size_t BSD = (size_t)BATCH * SEQ * DIM; // 33554432

typedef short  s16x8 __attribute__((ext_vector_type(8)));
typedef unsigned short u16x4 __attribute__((ext_vector_type(4)));
typedef float  f32x4 __attribute__((ext_vector_type(4)));

__device__ __forceinline__ unsigned short f2bf(float f) {
  union { float f; unsigned int u; } v; v.f = f;
  unsigned int r = v.u + 0x7fffu + ((v.u >> 16) & 1u);  // RNE
  return (unsigned short)(r >> 16);
}
__device__ __forceinline__ float bf2f(unsigned short h) {
  union { unsigned int u; float f; } v; v.u = ((unsigned int)h) << 16; return v.f;
}

__device__ __forceinline__ void gload_lds16(const void* g, void* l) {
  __builtin_amdgcn_global_load_lds(
      (const __attribute__((address_space(1))) void*)g,
      (__attribute__((address_space(3))) void*)l, 16, 0, 0);
}

// ---- L3-coherent helpers (proven in R3/R5) ----
#define HLOAD(dst, base, IMM)                                              \
  asm volatile("global_load_dwordx4 %0, %1, off offset:" IMM " sc0 sc1"    \
               : "=v"(dst) : "v"(base))
#define HL8(arr, base)        \
  HLOAD(arr[0], base, "0");   \
  HLOAD(arr[1], base, "64");  \
  HLOAD(arr[2], base, "128"); \
  HLOAD(arr[3], base, "192"); \
  HLOAD(arr[4], base, "256"); \
  HLOAD(arr[5], base, "320"); \
  HLOAD(arr[6], base, "384"); \
  HLOAD(arr[7], base, "448")

__device__ __forceinline__ void cstore8(void* p, u16x4 v) {
  asm volatile("global_store_dwordx2 %0, %1, off sc0 sc1"
               :: "v"(p), "v"(v) : "memory");
}
__device__ __forceinline__ void cstore4(void* p, int v) {
  asm volatile("global_store_dword %0, %1, off sc0 sc1"
               :: "v"(p), "v"(v) : "memory");
}
__device__ __forceinline__ void cstore4u(void* p, unsigned v) {
  asm volatile("global_store_dword %0, %1, off sc0 sc1"
               :: "v"(p), "v"(v) : "memory");
}
__device__ __forceinline__ int cload4(const void* p) {
  int v;
  asm volatile("global_load_dword %0, %1, off sc0 sc1\n\ts_waitcnt vmcnt(0)"
               : "=v"(v) : "v"(p) : "memory");
  return v;
}

// ---------------- prep kernels ----------------
__global__ void split_x_kernel(const float* __restrict__ x,
                               unsigned short* __restrict__ xh,
                               unsigned short* __restrict__ xl, long n4) {
  long i = (long)blockIdx.x * blockDim.x + threadIdx.x;
  const long stride = (long)gridDim.x * blockDim.x;
  for (; i < n4; i += stride) {
    f32x4 v = *(const f32x4*)&x[i * 4];
    u16x4 vh, vl;
#pragma unroll
    for (int j = 0; j < 4; ++j) {
      unsigned short hb = f2bf(v[j]);
      vh[j] = hb; vl[j] = f2bf(v[j] - bf2f(hb));
    }
    *(u16x4*)&xh[i * 4] = vh;
    *(u16x4*)&xl[i * 4] = vl;
  }
}

__global__ void split_w_kernel(const float* __restrict__ Wg,
                               const float* __restrict__ Wi,
                               unsigned short* __restrict__ wh,
                               unsigned short* __restrict__ wl) {
  long i = (long)blockIdx.x * blockDim.x + threadIdx.x; // 524288 float4 groups
  if (i >= (long)(2048 * 1024 / 4)) return;
  long flat = i * 4;
  int row = (int)(flat >> 10);
  int col = (int)(flat & 1023);
  const float* src = (row < 1024) ? &Wg[(size_t)row * 1024 + col]
                                  : &Wi[(size_t)(row - 1024) * 1024 + col];
  f32x4 v = *(const f32x4*)src;
  u16x4 vh, vl;
#pragma unroll
  for (int j = 0; j < 4; ++j) {
    unsigned short hb = f2bf(v[j]);
    vh[j] = hb; vl[j] = f2bf(v[j] - bf2f(hb));
  }
  *(u16x4*)&wh[flat] = vh;
  *(u16x4*)&wl[flat] = vl;
}

// zero h (both parities, all groups) + packed flags, all via sc0sc1 (L3).
// h_hi/h_lo: [2 parity][8 group][4 batch][1024 e] ushort = 65536 each.
// flags: 8 groups x 4 octets x 16 ints (first 8 used) = 512 ints.
__global__ void init_kernel(unsigned short* h_hi, unsigned short* h_lo,
                            int* flags) {
  int i = blockIdx.x * blockDim.x + threadIdx.x;  // 16384 launched
  u16x4 z4 = {0, 0, 0, 0};
  if (i < 16384) {
    cstore8(h_hi + (size_t)i * 4, z4);
    cstore8(h_lo + (size_t)i * 4, z4);
  }
  if (i < 512) cstore4(flags + i, 0);
}

// ---------------- fused G/P GEMM (split-bf16, 3-term) ----------------
__global__ __launch_bounds__(256) void gemm_gp_kernel(
    const unsigned short* __restrict__ xh, const unsigned short* __restrict__ xl,
    const unsigned short* __restrict__ wh, const unsigned short* __restrict__ wl,
    const float* __restrict__ bg, const float* __restrict__ bi,
    float* __restrict__ G, float* __restrict__ P) {
  __shared__ unsigned short sAh[128 * 32], sAl[128 * 32], sBh[128 * 32], sBl[128 * 32];
  const int tid = threadIdx.x;
  const int w = tid >> 6, l = tid & 63;
  const int wr = w >> 1, wc = w & 1;
  const int lr = l & 15, lk8 = (l >> 4) * 8;
  const size_t rBase = (size_t)blockIdx.x * 128;
  const int cBase = blockIdx.y * 128;

  f32x4 acc[4][4];
  f32x4 z = {0.f, 0.f, 0.f, 0.f};
#pragma unroll
  for (int m = 0; m < 4; ++m)
#pragma unroll
    for (int n = 0; n < 4; ++n) acc[m][n] = z;

  for (int kb = 0; kb < 32; ++kb) {
    const int k0 = kb * 32;
#pragma unroll
    for (int i = 0; i < 2; ++i) {
      const int chunk = w * 128 + i * 64 + l;
      const int row = chunk >> 2;
      const int c8 = (chunk & 3) * 8;
      gload_lds16(xh + (rBase + row) * 1024 + k0 + c8, &sAh[chunk * 8]);
      gload_lds16(xl + (rBase + row) * 1024 + k0 + c8, &sAl[chunk * 8]);
      gload_lds16(wh + (size_t)(cBase + row) * 1024 + k0 + c8, &sBh[chunk * 8]);
      gload_lds16(wl + (size_t)(cBase + row) * 1024 + k0 + c8, &sBl[chunk * 8]);
    }
    __syncthreads();

    s16x8 ah[4], al[4], bh[4], bl[4];
#pragma unroll
    for (int m = 0; m < 4; ++m) {
      ah[m] = *(const s16x8*)&sAh[(wr * 64 + m * 16 + lr) * 32 + lk8];
      al[m] = *(const s16x8*)&sAl[(wr * 64 + m * 16 + lr) * 32 + lk8];
    }
#pragma unroll
    for (int n = 0; n < 4; ++n) {
      bh[n] = *(const s16x8*)&sBh[(wc * 64 + n * 16 + lr) * 32 + lk8];
      bl[n] = *(const s16x8*)&sBl[(wc * 64 + n * 16 + lr) * 32 + lk8];
    }
#pragma unroll
    for (int m = 0; m < 4; ++m)
#pragma unroll
      for (int n = 0; n < 4; ++n)
        acc[m][n] = __builtin_amdgcn_mfma_f32_16x16x32_bf16(ah[m], bh[n], acc[m][n], 0, 0, 0);
#pragma unroll
    for (int m = 0; m < 4; ++m)
#pragma unroll
      for (int n = 0; n < 4; ++n)
        acc[m][n] = __builtin_amdgcn_mfma_f32_16x16x32_bf16(al[m], bh[n], acc[m][n], 0, 0, 0);
#pragma unroll
    for (int m = 0; m < 4; ++m)
#pragma unroll
      for (int n = 0; n < 4; ++n)
        acc[m][n] = __builtin_amdgcn_mfma_f32_16x16x32_bf16(ah[m], bl[n], acc[m][n], 0, 0, 0);
    __syncthreads();
  }

  const bool isG = (cBase < 1024);
#pragma unroll
  for (int m = 0; m < 4; ++m) {
#pragma unroll
    for (int n = 0; n < 4; ++n) {
      const int col = cBase + wc * 64 + n * 16 + lr;
      const size_t row0 = rBase + wr * 64 + m * 16 + (l >> 4) * 4;
#pragma unroll
      for (int i = 0; i < 4; ++i) {
        float v = acc[m][n][i];
        if (isG) {
          v += bg[col];
          v = 1.f / (1.f + expf(-v));
          G[(row0 + i) * 1024 + col] = v;
        } else {
          v += bi[col - 1024];
          P[(row0 + i) * 1024 + (col - 1024)] = v;
        }
      }
    }
  }
}

// ---------------- persistent recurrence kernel (v10 = v5 + 2 deltas) ------
// 256 WGs x 256 thr. group g = bid>>5 (batches 4g..4g+3), rank = bid&31
// (e-rows rank*32..+32). Wave kq = K-quarter, polls its 8 producers.
// h layout: [parity][group][batch(4)][1024] bf16 hi / lo.
// flags packed: flags[(g*4+oct)*16 + (rank&7)] — one 32B region per octet.
__global__ __launch_bounds__(256) void recur_kernel(
    const float* __restrict__ Ws, const float* __restrict__ bs,
    const float* __restrict__ G, float* out,
    unsigned short* h_hi, unsigned short* h_lo, int* flags) {
  __shared__ float part[2 * 4 * 4 * 32];  // [parity][kq][batch][32 e]
  const int g = blockIdx.x >> 5;
  const int rank = blockIdx.x & 31;
  const int tid = threadIdx.x;
  const int kq = tid >> 6, l = tid & 63;
  const int lr = l & 15, lh4 = l >> 4;

  // ---- Ws fragments -> registers (rank's 32 rows, wave's K-quarter) ----
  s16x8 bhi[2][8], blo[2][8];
#pragma unroll
  for (int nt = 0; nt < 2; ++nt) {
#pragma unroll
    for (int c = 0; c < 8; ++c) {
      const int e = rank * 32 + nt * 16 + lr;
      const int k = kq * 256 + c * 32 + lh4 * 8;
      const float* src = Ws + (size_t)e * DIM + k;
      f32x4 v0 = *(const f32x4*)src;
      f32x4 v1 = *(const f32x4*)(src + 4);
      s16x8 vh, vl;
#pragma unroll
      for (int j = 0; j < 4; ++j) {
        unsigned short hb = f2bf(v0[j]);
        vh[j] = (short)hb;
        vl[j] = (short)f2bf(v0[j] - bf2f(hb));
        unsigned short hb2 = f2bf(v1[j]);
        vh[4 + j] = (short)hb2;
        vl[4 + j] = (short)f2bf(v1[j] - bf2f(hb2));
      }
      bhi[nt][c] = vh; blo[nt][c] = vl;
    }
  }

  // ---- wave0 epilogue state: lane handles (batch=lh4, e=egl..egl+1) ----
  float hold0 = 0.f, hold1 = 0.f;
  float2 bs2 = {0.f, 0.f};
  size_t gpi = 0;
  int bgl = 0, egl = 0;
  if (tid < 64) {
    bgl = g * 4 + lh4;
    egl = rank * 32 + lr * 2;
    bs2 = *(const float2*)&bs[egl];
    gpi = ((size_t)bgl * SEQ) * DIM + egl;
  }
  float2 gA = {0, 0}, pA = {0, 0}, gB = {0, 0}, pB = {0, 0};
  if (tid < 64) { gA = *(const float2*)&G[gpi]; pA = *(const float2*)&out[gpi]; }

  // per-lane h-load base (element units); batch row = lr (<4 valid)
  const int lane_off = lr * 1024 + kq * 256 + lh4 * 8;
  // packed flags: consumer wave kq polls octet kq of its group (8 dwords in 32B)
  const int* fp = flags + ((g * 4 + kq) << 4) + (l & 7);
  int* myflag = flags + ((g * 4 + (rank >> 3)) << 4) + (rank & 7);

  auto body = [&](int t, float2& gc, float2& pc, float2& gn, float2& pn) {
    // ---- poll own 8 producers (single 32B segment per iteration) ----
    {
      int v;
      do { v = cload4(fp); } while (__any(v < t));
    }
    __builtin_amdgcn_sched_barrier(0);

    // ---- load h_t fragments (sc0sc1, coalesced) ----
    const unsigned short* Hh =
        h_hi + (size_t)(((t & 1) * 8 + g) * 4) * 1024 + lane_off;
    const unsigned short* Hl =
        h_lo + (size_t)(((t & 1) * 8 + g) * 4) * 1024 + lane_off;
    s16x8 ah[8], al[8];
    if (lr < 4) {
      HL8(ah, Hh);
      HL8(al, Hl);
    } else {
      s16x8 z8 = {0, 0, 0, 0, 0, 0, 0, 0};
#pragma unroll
      for (int c = 0; c < 8; ++c) { ah[c] = z8; al[c] = z8; }
    }
    asm volatile("s_waitcnt vmcnt(0)" ::: "memory");
    __builtin_amdgcn_sched_barrier(0);

    // ---- 3-term split-bf16 MFMA (A rows = batches, 4 valid) ----
    f32x4 z = {0.f, 0.f, 0.f, 0.f};
    f32x4 aA[2], aB[2], aC[2];
#pragma unroll
    for (int nt = 0; nt < 2; ++nt) { aA[nt] = z; aB[nt] = z; aC[nt] = z; }
#pragma unroll
    for (int c = 0; c < 8; ++c) {
#pragma unroll
      for (int nt = 0; nt < 2; ++nt) {
        aA[nt] = __builtin_amdgcn_mfma_f32_16x16x32_bf16(ah[c], bhi[nt][c], aA[nt], 0, 0, 0);
        aB[nt] = __builtin_amdgcn_mfma_f32_16x16x32_bf16(al[c], bhi[nt][c], aB[nt], 0, 0, 0);
        aC[nt] = __builtin_amdgcn_mfma_f32_16x16x32_bf16(ah[c], blo[nt][c], aC[nt], 0, 0, 0);
      }
    }

    // ---- partials to LDS (valid batches: lanes lh4==0, regs i=0..3) ----
    if (lh4 == 0) {
#pragma unroll
      for (int nt = 0; nt < 2; ++nt) {
        f32x4 v = aA[nt] + aB[nt] + aC[nt];
#pragma unroll
        for (int i = 0; i < 4; ++i)
          part[(t & 1) * 512 + kq * 128 + i * 32 + nt * 16 + lr] = v[i];
      }
    }
    asm volatile("s_waitcnt lgkmcnt(0)" ::: "memory");
    __builtin_amdgcn_s_barrier();
    __builtin_amdgcn_sched_barrier(0);

    // ---- wave0: K-reduce + epilogue + publish ----
    if (tid < 64) {
      const int b = lh4, e2 = lr * 2;
      const float* pp = &part[(t & 1) * 512 + b * 32 + e2];
      float2 r0 = *(const float2*)&pp[0];
      float2 r1 = *(const float2*)&pp[128];
      float2 r2 = *(const float2*)&pp[256];
      float2 r3 = *(const float2*)&pp[384];
      const float s0 = r0.x + r1.x + r2.x + r3.x;
      const float s1 = r0.y + r1.y + r2.y + r3.y;
      const float mix0 = s0 + bs2.x + pc.x;
      const float mix1 = s1 + bs2.y + pc.y;
      const float h0 = gc.x * mix0 + (1.f - gc.x) * hold0;
      const float h1 = gc.y * mix1 + (1.f - gc.y) * hold1;
      hold0 = h0; hold1 = h1;

      const unsigned short hb0 = f2bf(h0), hb1 = f2bf(h1);
      const unsigned short lb0 = f2bf(h0 - bf2f(hb0)), lb1 = f2bf(h1 - bf2f(hb1));
      const size_t hoff =
          (size_t)((((t + 1) & 1) * 8 + g) * 4 + b) * 1024 + egl;
      cstore4u(h_hi + hoff, (unsigned)hb0 | ((unsigned)hb1 << 16));
      cstore4u(h_lo + hoff, (unsigned)lb0 | ((unsigned)lb1 << 16));
      asm volatile("s_waitcnt vmcnt(0)" ::: "memory");  // h visible before flag
      if (l == 0 && t < SEQ - 1) cstore4(myflag, t + 1);

      float2 ev; ev.x = h0; ev.y = h1;
      *(float2*)&out[gpi] = ev;  // emitted (overwrites consumed P slot)
      if (t == SEQ - 1)
        *(float2*)&out[BSD + (size_t)bgl * DIM + egl] = ev;

      // ---- prefetch g,p for t+1 AFTER publish (never delays the ack) ----
      const size_t gpn = gpi + ((t + 1 < SEQ) ? DIM : 0);
      gn = *(const float2*)&G[gpn];
      pn = *(const float2*)&out[gpn];
      gpi = gpn;
    }
  };

#pragma unroll 1
  for (int t = 0; t < SEQ; t += 2) {
    body(t, gA, pA, gB, pB);
    body(t + 1, gB, pB, gA, pA);
  }
}

// ---------------- launch ----------------
extern "C" void kernel_launch(void* const* d_in, const int* in_sizes, int n_in,
                              void* d_out, int out_size, void* d_ws, size_t ws_size,
                              hipStream_t stream) {
  (void)in_sizes; (void)n_in; (void)out_size; (void)ws_size;
  const float* x  = (const float*)d_in[0];
  const float* Wg = (const float*)d_in[1];
  const float* bg = (const float*)d_in[2];
  const float* Ws = (const float*)d_in[3];
  const float* bs = (const float*)d_in[4];
  const float* Wi = (const float*)d_in[5];
  const float* bi = (const float*)d_in[6];
  float* out = (float*)d_out;
  char* ws = (char*)d_ws;

  unsigned short* xh   = (unsigned short*)(ws);              // 64 MB
  unsigned short* xl   = (unsigned short*)(ws + 67108864);   // 64 MB
  unsigned short* wh   = (unsigned short*)(ws + 134217728);  // 4 MB (dead after gemm)
  unsigned short* wl   = (unsigned short*)(ws + 138412032);  // 4 MB (dead after gemm)
  float*          G    = (float*)(ws + 142606336);           // 128 MB
  unsigned short* h_hi = (unsigned short*)(ws + 276824064);  // 128 KB [2][8][4][1024]
  unsigned short* h_lo = (unsigned short*)(ws + 276955136);  // 128 KB
  int*            flags= (int*)(ws + 134217728);             // 2 KB (overlaps wh; init AFTER gemm)

  hipLaunchKernelGGL(split_x_kernel, dim3(4096), dim3(256), 0, stream,
                     x, xh, xl, (long)(BSD / 4));
  hipLaunchKernelGGL(split_w_kernel, dim3(2048), dim3(256), 0, stream, Wg, Wi, wh, wl);
  hipLaunchKernelGGL(gemm_gp_kernel, dim3(256, 16), dim3(256), 0, stream,
                     xh, xl, wh, wl, bg, bi, G, out);
  hipLaunchKernelGGL(init_kernel, dim3(64), dim3(256), 0, stream, h_hi, h_lo, flags);
  hipLaunchKernelGGL(recur_kernel, dim3(256), dim3(256), 0, stream,
                     Ws, bs, G, out, h_hi, h_lo, flags);
}

// Round 12
// 3786.229 us; speedup vs baseline: 1.3320x; 1.3320x over previous
//
#include <hip/hip_runtime.h>
#include <cstdint>

// B=32, S=1024, D=1024 ContractiveSequenceMixer.
// R12: R5-EXACT recurrence (champion: 3240us) with ONE change: all cross-WG
// exchange ops use sc1 ONLY (= agent/device scope) instead of sc0 sc1
// (= system scope). Per the gfx940+ memory model, (sc1,sc0) encodes SCOPE:
// sc0-only ~ workgroup scope (=> R4/R11 hangs: stores never became visible),
// sc1 = agent (sufficient: one GPU), sc0sc1 = system (host-coherent --
// what R3..R10 overpaid for on every poll/load/store).

#define BATCH 32
#define SEQ   1024
#define DIM   1024
static const size_t BSD = (size_t)BATCH * SEQ * DIM; // 33554432

typedef short  s16x8 __attribute__((ext_vector_type(8)));
typedef unsigned short u16x4 __attribute__((ext_vector_type(4)));
typedef float  f32x4 __attribute__((ext_vector_type(4)));

__device__ __forceinline__ unsigned short f2bf(float f) {
  union { float f; unsigned int u; } v; v.f = f;
  unsigned int r = v.u + 0x7fffu + ((v.u >> 16) & 1u);  // RNE
  return (unsigned short)(r >> 16);
}
__device__ __forceinline__ float bf2f(unsigned short h) {
  union { unsigned int u; float f; } v; v.u = ((unsigned int)h) << 16; return v.f;
}

__device__ __forceinline__ void gload_lds16(const void* g, void* l) {
  __builtin_amdgcn_global_load_lds(
      (const __attribute__((address_space(1))) void*)g,
      (__attribute__((address_space(3))) void*)l, 16, 0, 0);
}

// ---- agent-scope (device-coherent) helpers: sc1 only ----
#define HLOAD(dst, base, IMM)                                          \
  asm volatile("global_load_dwordx4 %0, %1, off offset:" IMM " sc1"    \
               : "=v"(dst) : "v"(base))
#define HL8(arr, base)        \
  HLOAD(arr[0], base, "0");   \
  HLOAD(arr[1], base, "64");  \
  HLOAD(arr[2], base, "128"); \
  HLOAD(arr[3], base, "192"); \
  HLOAD(arr[4], base, "256"); \
  HLOAD(arr[5], base, "320"); \
  HLOAD(arr[6], base, "384"); \
  HLOAD(arr[7], base, "448")

__device__ __forceinline__ void cstore8(void* p, u16x4 v) {
  asm volatile("global_store_dwordx2 %0, %1, off sc1"
               :: "v"(p), "v"(v) : "memory");
}
__device__ __forceinline__ void cstore4(void* p, int v) {
  asm volatile("global_store_dword %0, %1, off sc1"
               :: "v"(p), "v"(v) : "memory");
}
__device__ __forceinline__ void cstore4u(void* p, unsigned v) {
  asm volatile("global_store_dword %0, %1, off sc1"
               :: "v"(p), "v"(v) : "memory");
}
__device__ __forceinline__ int cload4(const void* p) {
  int v;
  asm volatile("global_load_dword %0, %1, off sc1\n\ts_waitcnt vmcnt(0)"
               : "=v"(v) : "v"(p) : "memory");
  return v;
}

// ---------------- prep kernels ----------------
__global__ void split_x_kernel(const float* __restrict__ x,
                               unsigned short* __restrict__ xh,
                               unsigned short* __restrict__ xl, long n4) {
  long i = (long)blockIdx.x * blockDim.x + threadIdx.x;
  const long stride = (long)gridDim.x * blockDim.x;
  for (; i < n4; i += stride) {
    f32x4 v = *(const f32x4*)&x[i * 4];
    u16x4 vh, vl;
#pragma unroll
    for (int j = 0; j < 4; ++j) {
      unsigned short hb = f2bf(v[j]);
      vh[j] = hb; vl[j] = f2bf(v[j] - bf2f(hb));
    }
    *(u16x4*)&xh[i * 4] = vh;
    *(u16x4*)&xl[i * 4] = vl;
  }
}

__global__ void split_w_kernel(const float* __restrict__ Wg,
                               const float* __restrict__ Wi,
                               unsigned short* __restrict__ wh,
                               unsigned short* __restrict__ wl) {
  long i = (long)blockIdx.x * blockDim.x + threadIdx.x; // 524288 float4 groups
  if (i >= (long)(2048 * 1024 / 4)) return;
  long flat = i * 4;
  int row = (int)(flat >> 10);
  int col = (int)(flat & 1023);
  const float* src = (row < 1024) ? &Wg[(size_t)row * 1024 + col]
                                  : &Wi[(size_t)(row - 1024) * 1024 + col];
  f32x4 v = *(const f32x4*)src;
  u16x4 vh, vl;
#pragma unroll
  for (int j = 0; j < 4; ++j) {
    unsigned short hb = f2bf(v[j]);
    vh[j] = hb; vl[j] = f2bf(v[j] - bf2f(hb));
  }
  *(u16x4*)&wh[flat] = vh;
  *(u16x4*)&wl[flat] = vl;
}

// zero h (both parities, all groups) + flags, all via sc1 (agent scope).
// h_hi/h_lo: [2 parity][8 group][4 batch][1024 e] ushort = 65536 each.
__global__ void init_kernel(unsigned short* h_hi, unsigned short* h_lo,
                            int* flags) {
  int i = blockIdx.x * blockDim.x + threadIdx.x;  // 16384 launched
  u16x4 z4 = {0, 0, 0, 0};
  if (i < 16384) {
    cstore8(h_hi + (size_t)i * 4, z4);
    cstore8(h_lo + (size_t)i * 4, z4);
  }
  if (i < 4096) cstore4(flags + i, 0);
}

// ---------------- fused G/P GEMM (split-bf16, 3-term) ----------------
__global__ __launch_bounds__(256) void gemm_gp_kernel(
    const unsigned short* __restrict__ xh, const unsigned short* __restrict__ xl,
    const unsigned short* __restrict__ wh, const unsigned short* __restrict__ wl,
    const float* __restrict__ bg, const float* __restrict__ bi,
    float* __restrict__ G, float* __restrict__ P) {
  __shared__ unsigned short sAh[128 * 32], sAl[128 * 32], sBh[128 * 32], sBl[128 * 32];
  const int tid = threadIdx.x;
  const int w = tid >> 6, l = tid & 63;
  const int wr = w >> 1, wc = w & 1;
  const int lr = l & 15, lk8 = (l >> 4) * 8;
  const size_t rBase = (size_t)blockIdx.x * 128;
  const int cBase = blockIdx.y * 128;

  f32x4 acc[4][4];
  f32x4 z = {0.f, 0.f, 0.f, 0.f};
#pragma unroll
  for (int m = 0; m < 4; ++m)
#pragma unroll
    for (int n = 0; n < 4; ++n) acc[m][n] = z;

  for (int kb = 0; kb < 32; ++kb) {
    const int k0 = kb * 32;
#pragma unroll
    for (int i = 0; i < 2; ++i) {
      const int chunk = w * 128 + i * 64 + l;
      const int row = chunk >> 2;
      const int c8 = (chunk & 3) * 8;
      gload_lds16(xh + (rBase + row) * 1024 + k0 + c8, &sAh[chunk * 8]);
      gload_lds16(xl + (rBase + row) * 1024 + k0 + c8, &sAl[chunk * 8]);
      gload_lds16(wh + (size_t)(cBase + row) * 1024 + k0 + c8, &sBh[chunk * 8]);
      gload_lds16(wl + (size_t)(cBase + row) * 1024 + k0 + c8, &sBl[chunk * 8]);
    }
    __syncthreads();

    s16x8 ah[4], al[4], bh[4], bl[4];
#pragma unroll
    for (int m = 0; m < 4; ++m) {
      ah[m] = *(const s16x8*)&sAh[(wr * 64 + m * 16 + lr) * 32 + lk8];
      al[m] = *(const s16x8*)&sAl[(wr * 64 + m * 16 + lr) * 32 + lk8];
    }
#pragma unroll
    for (int n = 0; n < 4; ++n) {
      bh[n] = *(const s16x8*)&sBh[(wc * 64 + n * 16 + lr) * 32 + lk8];
      bl[n] = *(const s16x8*)&sBl[(wc * 64 + n * 16 + lr) * 32 + lk8];
    }
#pragma unroll
    for (int m = 0; m < 4; ++m)
#pragma unroll
      for (int n = 0; n < 4; ++n)
        acc[m][n] = __builtin_amdgcn_mfma_f32_16x16x32_bf16(ah[m], bh[n], acc[m][n], 0, 0, 0);
#pragma unroll
    for (int m = 0; m < 4; ++m)
#pragma unroll
      for (int n = 0; n < 4; ++n)
        acc[m][n] = __builtin_amdgcn_mfma_f32_16x16x32_bf16(al[m], bh[n], acc[m][n], 0, 0, 0);
#pragma unroll
    for (int m = 0; m < 4; ++m)
#pragma unroll
      for (int n = 0; n < 4; ++n)
        acc[m][n] = __builtin_amdgcn_mfma_f32_16x16x32_bf16(ah[m], bl[n], acc[m][n], 0, 0, 0);
    __syncthreads();
  }

  const bool isG = (cBase < 1024);
#pragma unroll
  for (int m = 0; m < 4; ++m) {
#pragma unroll
    for (int n = 0; n < 4; ++n) {
      const int col = cBase + wc * 64 + n * 16 + lr;
      const size_t row0 = rBase + wr * 64 + m * 16 + (l >> 4) * 4;
#pragma unroll
      for (int i = 0; i < 4; ++i) {
        float v = acc[m][n][i];
        if (isG) {
          v += bg[col];
          v = 1.f / (1.f + expf(-v));
          G[(row0 + i) * 1024 + col] = v;
        } else {
          v += bi[col - 1024];
          P[(row0 + i) * 1024 + (col - 1024)] = v;
        }
      }
    }
  }
}

// ---------------- persistent recurrence kernel (v12 = v5 @ agent scope) ----
// 256 WGs x 256 thr. group g = bid>>5 (batches 4g..4g+3), rank = bid&31
// (e-rows rank*32..+32). Wave kq = K-quarter, polls its 8 producers.
// h layout: [parity][group][batch(4)][1024] bf16 hi / lo.
__global__ __launch_bounds__(256) void recur_kernel(
    const float* __restrict__ Ws, const float* __restrict__ bs,
    const float* __restrict__ G, float* out,
    unsigned short* h_hi, unsigned short* h_lo, int* flags) {
  __shared__ float part[2 * 4 * 4 * 32];  // [parity][kq][batch][32 e]
  const int g = blockIdx.x >> 5;
  const int rank = blockIdx.x & 31;
  const int tid = threadIdx.x;
  const int kq = tid >> 6, l = tid & 63;
  const int lr = l & 15, lh4 = l >> 4;

  // ---- Ws fragments -> registers (rank's 32 rows, wave's K-quarter) ----
  s16x8 bhi[2][8], blo[2][8];
#pragma unroll
  for (int nt = 0; nt < 2; ++nt) {
#pragma unroll
    for (int c = 0; c < 8; ++c) {
      const int e = rank * 32 + nt * 16 + lr;
      const int k = kq * 256 + c * 32 + lh4 * 8;
      const float* src = Ws + (size_t)e * DIM + k;
      f32x4 v0 = *(const f32x4*)src;
      f32x4 v1 = *(const f32x4*)(src + 4);
      s16x8 vh, vl;
#pragma unroll
      for (int j = 0; j < 4; ++j) {
        unsigned short hb = f2bf(v0[j]);
        vh[j] = (short)hb;
        vl[j] = (short)f2bf(v0[j] - bf2f(hb));
        unsigned short hb2 = f2bf(v1[j]);
        vh[4 + j] = (short)hb2;
        vl[4 + j] = (short)f2bf(v1[j] - bf2f(hb2));
      }
      bhi[nt][c] = vh; blo[nt][c] = vl;
    }
  }

  // ---- wave0 epilogue state: lane handles (batch=lh4, e=egl..egl+1) ----
  float hold0 = 0.f, hold1 = 0.f;
  float2 bs2 = {0.f, 0.f};
  size_t gpi = 0;
  int bgl = 0, egl = 0;
  if (tid < 64) {
    bgl = g * 4 + lh4;
    egl = rank * 32 + lr * 2;
    bs2 = *(const float2*)&bs[egl];
    gpi = ((size_t)bgl * SEQ) * DIM + egl;
  }
  float2 gA = {0, 0}, pA = {0, 0}, gB = {0, 0}, pB = {0, 0};
  if (tid < 64) { gA = *(const float2*)&G[gpi]; pA = *(const float2*)&out[gpi]; }

  // per-lane h-load base (element units); batch row = lr (<4 valid)
  const int lane_off = lr * 1024 + kq * 256 + lh4 * 8;
  const int* fp = flags + ((g << 5) + (kq << 3) + (l & 7)) * 16;
  int* myflag = flags + ((g << 5) + rank) * 16;

  auto body = [&](int t, float2& gc, float2& pc, float2& gn, float2& pn) {
    // ---- poll own 8 producers (>= t) ----
    {
      int v;
      do { v = cload4(fp); } while (__any(v < t));
    }
    __builtin_amdgcn_sched_barrier(0);

    // ---- load h_t fragments (sc1, coalesced) ----
    const unsigned short* Hh =
        h_hi + (size_t)(((t & 1) * 8 + g) * 4) * 1024 + lane_off;
    const unsigned short* Hl =
        h_lo + (size_t)(((t & 1) * 8 + g) * 4) * 1024 + lane_off;
    s16x8 ah[8], al[8];
    if (lr < 4) {
      HL8(ah, Hh);
      HL8(al, Hl);
    } else {
      s16x8 z8 = {0, 0, 0, 0, 0, 0, 0, 0};
#pragma unroll
      for (int c = 0; c < 8; ++c) { ah[c] = z8; al[c] = z8; }
    }
    asm volatile("s_waitcnt vmcnt(0)" ::: "memory");
    __builtin_amdgcn_sched_barrier(0);

    // ---- prefetch g,p for t+1 (plain cached loads; resolve during MFMA) ----
    if (tid < 64) {
      const size_t gpn = gpi + ((t + 1 < SEQ) ? DIM : 0);
      gn = *(const float2*)&G[gpn];
      pn = *(const float2*)&out[gpn];
    }

    // ---- 3-term split-bf16 MFMA (A rows = batches, 4 valid) ----
    f32x4 z = {0.f, 0.f, 0.f, 0.f};
    f32x4 aA[2], aB[2], aC[2];
#pragma unroll
    for (int nt = 0; nt < 2; ++nt) { aA[nt] = z; aB[nt] = z; aC[nt] = z; }
#pragma unroll
    for (int c = 0; c < 8; ++c) {
#pragma unroll
      for (int nt = 0; nt < 2; ++nt) {
        aA[nt] = __builtin_amdgcn_mfma_f32_16x16x32_bf16(ah[c], bhi[nt][c], aA[nt], 0, 0, 0);
        aB[nt] = __builtin_amdgcn_mfma_f32_16x16x32_bf16(al[c], bhi[nt][c], aB[nt], 0, 0, 0);
        aC[nt] = __builtin_amdgcn_mfma_f32_16x16x32_bf16(ah[c], blo[nt][c], aC[nt], 0, 0, 0);
      }
    }

    // ---- partials to LDS (valid batches: lanes lh4==0, regs i=0..3) ----
    if (lh4 == 0) {
#pragma unroll
      for (int nt = 0; nt < 2; ++nt) {
        f32x4 v = aA[nt] + aB[nt] + aC[nt];
#pragma unroll
        for (int i = 0; i < 4; ++i)
          part[(t & 1) * 512 + kq * 128 + i * 32 + nt * 16 + lr] = v[i];
      }
    }
    asm volatile("s_waitcnt lgkmcnt(0)" ::: "memory");
    __builtin_amdgcn_s_barrier();
    __builtin_amdgcn_sched_barrier(0);

    // ---- wave0: K-reduce + epilogue + publish ----
    if (tid < 64) {
      const int b = lh4, e2 = lr * 2;
      const float* pp = &part[(t & 1) * 512 + b * 32 + e2];
      float2 r0 = *(const float2*)&pp[0];
      float2 r1 = *(const float2*)&pp[128];
      float2 r2 = *(const float2*)&pp[256];
      float2 r3 = *(const float2*)&pp[384];
      const float s0 = r0.x + r1.x + r2.x + r3.x;
      const float s1 = r0.y + r1.y + r2.y + r3.y;
      const float mix0 = s0 + bs2.x + pc.x;
      const float mix1 = s1 + bs2.y + pc.y;
      const float h0 = gc.x * mix0 + (1.f - gc.x) * hold0;
      const float h1 = gc.y * mix1 + (1.f - gc.y) * hold1;
      hold0 = h0; hold1 = h1;

      const unsigned short hb0 = f2bf(h0), hb1 = f2bf(h1);
      const unsigned short lb0 = f2bf(h0 - bf2f(hb0)), lb1 = f2bf(h1 - bf2f(hb1));
      const size_t hoff =
          (size_t)((((t + 1) & 1) * 8 + g) * 4 + b) * 1024 + egl;
      cstore4u(h_hi + hoff, (unsigned)hb0 | ((unsigned)hb1 << 16));
      cstore4u(h_lo + hoff, (unsigned)lb0 | ((unsigned)lb1 << 16));
      asm volatile("s_waitcnt vmcnt(0)" ::: "memory");  // h visible before flag
      if (l == 0 && t < SEQ - 1) cstore4(myflag, t + 1);

      float2 ev; ev.x = h0; ev.y = h1;
      *(float2*)&out[gpi] = ev;  // emitted (overwrites consumed P slot)
      if (t == SEQ - 1)
        *(float2*)&out[BSD + (size_t)bgl * DIM + egl] = ev;
      gpi += ((t + 1 < SEQ) ? DIM : 0);
    }
  };

#pragma unroll 1
  for (int t = 0; t < SEQ; t += 2) {
    body(t, gA, pA, gB, pB);
    body(t + 1, gB, pB, gA, pA);
  }
}

// ---------------- launch ----------------
extern "C" void kernel_launch(void* const* d_in, const int* in_sizes, int n_in,
                              void* d_out, int out_size, void* d_ws, size_t ws_size,
                              hipStream_t stream) {
  (void)in_sizes; (void)n_in; (void)out_size; (void)ws_size;
  const float* x  = (const float*)d_in[0];
  const float* Wg = (const float*)d_in[1];
  const float* bg = (const float*)d_in[2];
  const float* Ws = (const float*)d_in[3];
  const float* bs = (const float*)d_in[4];
  const float* Wi = (const float*)d_in[5];
  const float* bi = (const float*)d_in[6];
  float* out = (float*)d_out;
  char* ws = (char*)d_ws;

  unsigned short* xh   = (unsigned short*)(ws);              // 64 MB
  unsigned short* xl   = (unsigned short*)(ws + 67108864);   // 64 MB
  unsigned short* wh   = (unsigned short*)(ws + 134217728);  // 4 MB (dead after gemm)
  unsigned short* wl   = (unsigned short*)(ws + 138412032);  // 4 MB (dead after gemm)
  float*          G    = (float*)(ws + 142606336);           // 128 MB
  unsigned short* h_hi = (unsigned short*)(ws + 276824064);  // 128 KB [2][8][4][1024]
  unsigned short* h_lo = (unsigned short*)(ws + 276955136);  // 128 KB
  int*            flags= (int*)(ws + 134217728);             // 16 KB (overlaps wh; init AFTER gemm)

  hipLaunchKernelGGL(split_x_kernel, dim3(4096), dim3(256), 0, stream,
                     x, xh, xl, (long)(BSD / 4));
  hipLaunchKernelGGL(split_w_kernel, dim3(2048), dim3(256), 0, stream, Wg, Wi, wh, wl);
  hipLaunchKernelGGL(gemm_gp_kernel, dim3(256, 16), dim3(256), 0, stream,
                     xh, xl, wh, wl, bg, bi, G, out);
  hipLaunchKernelGGL(init_kernel, dim3(64), dim3(256), 0, stream, h_hi, h_lo, flags);
  hipLaunchKernelGGL(recur_kernel, dim3(256), dim3(256), 0, stream,
                     Ws, bs, G, out, h_hi, h_lo, flags);
}

// Round 15
// 3707.760 us; speedup vs baseline: 1.3601x; 1.0212x over previous
//
#include <hip/hip_runtime.h>
#include <cstdint>

// B=32, S=1024, D=1024 ContractiveSequenceMixer.
// R15 = R12 restored (session champion: 3786us total, absmax 16.0).
//
// Final structure:
//  - split-bf16 3-term numerics throughout (hi+lo bf16; err ~1e-5 rel).
//  - fused MFMA GEMM (K=1024, N=2048) -> G (sigmoid gates, ws) and
//    P (input proj, written into d_out; recurrence consumes then overwrites
//    with emitted). ~450us at ~914 TF-equiv (m97-structure ceiling).
//  - persistent 256-WG recurrence: group g owns 4 batches, rank owns 32
//    e-rows, wave kq owns a K-quarter (Ws slice in VGPRs, zero reload).
//    h exchange via agent-scope (sc1) stores/loads at the L3 coherence
//    point; per-producer 64B-spread flags, ack-then-flag publish.
//    3.16us/step = ~3.5 serialized fabric RTTs -- the latency floor
//    (7 protocol variants converge here; counters show ~90% stall).
// Falsified along the way: per-step cache fences (R1), per-lane atomics
// (R2), full-data polling (R6), speculative loads (R8), split publish (R9),
// packed flags (R10), sc0-only L2 exchange (R4/R11 hang: sc0 = workgroup
// scope), system-vs-agent scope (R12: no delta), fused gemm overlap
// (R13 hang / R14 NaN: unresolved sync hazard).

#define BATCH 32
#define SEQ   1024
#define DIM   1024
static const size_t BSD = (size_t)BATCH * SEQ * DIM; // 33554432

typedef short  s16x8 __attribute__((ext_vector_type(8)));
typedef unsigned short u16x4 __attribute__((ext_vector_type(4)));
typedef float  f32x4 __attribute__((ext_vector_type(4)));

__device__ __forceinline__ unsigned short f2bf(float f) {
  union { float f; unsigned int u; } v; v.f = f;
  unsigned int r = v.u + 0x7fffu + ((v.u >> 16) & 1u);  // RNE
  return (unsigned short)(r >> 16);
}
__device__ __forceinline__ float bf2f(unsigned short h) {
  union { unsigned int u; float f; } v; v.u = ((unsigned int)h) << 16; return v.f;
}

__device__ __forceinline__ void gload_lds16(const void* g, void* l) {
  __builtin_amdgcn_global_load_lds(
      (const __attribute__((address_space(1))) void*)g,
      (__attribute__((address_space(3))) void*)l, 16, 0, 0);
}

// ---- agent-scope (device-coherent) helpers: sc1 only ----
#define HLOAD(dst, base, IMM)                                          \
  asm volatile("global_load_dwordx4 %0, %1, off offset:" IMM " sc1"    \
               : "=v"(dst) : "v"(base))
#define HL8(arr, base)        \
  HLOAD(arr[0], base, "0");   \
  HLOAD(arr[1], base, "64");  \
  HLOAD(arr[2], base, "128"); \
  HLOAD(arr[3], base, "192"); \
  HLOAD(arr[4], base, "256"); \
  HLOAD(arr[5], base, "320"); \
  HLOAD(arr[6], base, "384"); \
  HLOAD(arr[7], base, "448")

__device__ __forceinline__ void cstore8(void* p, u16x4 v) {
  asm volatile("global_store_dwordx2 %0, %1, off sc1"
               :: "v"(p), "v"(v) : "memory");
}
__device__ __forceinline__ void cstore4(void* p, int v) {
  asm volatile("global_store_dword %0, %1, off sc1"
               :: "v"(p), "v"(v) : "memory");
}
__device__ __forceinline__ void cstore4u(void* p, unsigned v) {
  asm volatile("global_store_dword %0, %1, off sc1"
               :: "v"(p), "v"(v) : "memory");
}
__device__ __forceinline__ int cload4(const void* p) {
  int v;
  asm volatile("global_load_dword %0, %1, off sc1\n\ts_waitcnt vmcnt(0)"
               : "=v"(v) : "v"(p) : "memory");
  return v;
}

// ---------------- prep kernels ----------------
__global__ void split_x_kernel(const float* __restrict__ x,
                               unsigned short* __restrict__ xh,
                               unsigned short* __restrict__ xl, long n4) {
  long i = (long)blockIdx.x * blockDim.x + threadIdx.x;
  const long stride = (long)gridDim.x * blockDim.x;
  for (; i < n4; i += stride) {
    f32x4 v = *(const f32x4*)&x[i * 4];
    u16x4 vh, vl;
#pragma unroll
    for (int j = 0; j < 4; ++j) {
      unsigned short hb = f2bf(v[j]);
      vh[j] = hb; vl[j] = f2bf(v[j] - bf2f(hb));
    }
    *(u16x4*)&xh[i * 4] = vh;
    *(u16x4*)&xl[i * 4] = vl;
  }
}

__global__ void split_w_kernel(const float* __restrict__ Wg,
                               const float* __restrict__ Wi,
                               unsigned short* __restrict__ wh,
                               unsigned short* __restrict__ wl) {
  long i = (long)blockIdx.x * blockDim.x + threadIdx.x; // 524288 float4 groups
  if (i >= (long)(2048 * 1024 / 4)) return;
  long flat = i * 4;
  int row = (int)(flat >> 10);
  int col = (int)(flat & 1023);
  const float* src = (row < 1024) ? &Wg[(size_t)row * 1024 + col]
                                  : &Wi[(size_t)(row - 1024) * 1024 + col];
  f32x4 v = *(const f32x4*)src;
  u16x4 vh, vl;
#pragma unroll
  for (int j = 0; j < 4; ++j) {
    unsigned short hb = f2bf(v[j]);
    vh[j] = hb; vl[j] = f2bf(v[j] - bf2f(hb));
  }
  *(u16x4*)&wh[flat] = vh;
  *(u16x4*)&wl[flat] = vl;
}

// zero h (both parities, all groups) + flags, all via sc1 (agent scope).
// h_hi/h_lo: [2 parity][8 group][4 batch][1024 e] ushort = 65536 each.
__global__ void init_kernel(unsigned short* h_hi, unsigned short* h_lo,
                            int* flags) {
  int i = blockIdx.x * blockDim.x + threadIdx.x;  // 16384 launched
  u16x4 z4 = {0, 0, 0, 0};
  if (i < 16384) {
    cstore8(h_hi + (size_t)i * 4, z4);
    cstore8(h_lo + (size_t)i * 4, z4);
  }
  if (i < 4096) cstore4(flags + i, 0);
}

// ---------------- fused G/P GEMM (split-bf16, 3-term) ----------------
__global__ __launch_bounds__(256) void gemm_gp_kernel(
    const unsigned short* __restrict__ xh, const unsigned short* __restrict__ xl,
    const unsigned short* __restrict__ wh, const unsigned short* __restrict__ wl,
    const float* __restrict__ bg, const float* __restrict__ bi,
    float* __restrict__ G, float* __restrict__ P) {
  __shared__ unsigned short sAh[128 * 32], sAl[128 * 32], sBh[128 * 32], sBl[128 * 32];
  const int tid = threadIdx.x;
  const int w = tid >> 6, l = tid & 63;
  const int wr = w >> 1, wc = w & 1;
  const int lr = l & 15, lk8 = (l >> 4) * 8;
  const size_t rBase = (size_t)blockIdx.x * 128;
  const int cBase = blockIdx.y * 128;

  f32x4 acc[4][4];
  f32x4 z = {0.f, 0.f, 0.f, 0.f};
#pragma unroll
  for (int m = 0; m < 4; ++m)
#pragma unroll
    for (int n = 0; n < 4; ++n) acc[m][n] = z;

  for (int kb = 0; kb < 32; ++kb) {
    const int k0 = kb * 32;
#pragma unroll
    for (int i = 0; i < 2; ++i) {
      const int chunk = w * 128 + i * 64 + l;
      const int row = chunk >> 2;
      const int c8 = (chunk & 3) * 8;
      gload_lds16(xh + (rBase + row) * 1024 + k0 + c8, &sAh[chunk * 8]);
      gload_lds16(xl + (rBase + row) * 1024 + k0 + c8, &sAl[chunk * 8]);
      gload_lds16(wh + (size_t)(cBase + row) * 1024 + k0 + c8, &sBh[chunk * 8]);
      gload_lds16(wl + (size_t)(cBase + row) * 1024 + k0 + c8, &sBl[chunk * 8]);
    }
    __syncthreads();

    s16x8 ah[4], al[4], bh[4], bl[4];
#pragma unroll
    for (int m = 0; m < 4; ++m) {
      ah[m] = *(const s16x8*)&sAh[(wr * 64 + m * 16 + lr) * 32 + lk8];
      al[m] = *(const s16x8*)&sAl[(wr * 64 + m * 16 + lr) * 32 + lk8];
    }
#pragma unroll
    for (int n = 0; n < 4; ++n) {
      bh[n] = *(const s16x8*)&sBh[(wc * 64 + n * 16 + lr) * 32 + lk8];
      bl[n] = *(const s16x8*)&sBl[(wc * 64 + n * 16 + lr) * 32 + lk8];
    }
#pragma unroll
    for (int m = 0; m < 4; ++m)
#pragma unroll
      for (int n = 0; n < 4; ++n)
        acc[m][n] = __builtin_amdgcn_mfma_f32_16x16x32_bf16(ah[m], bh[n], acc[m][n], 0, 0, 0);
#pragma unroll
    for (int m = 0; m < 4; ++m)
#pragma unroll
      for (int n = 0; n < 4; ++n)
        acc[m][n] = __builtin_amdgcn_mfma_f32_16x16x32_bf16(al[m], bh[n], acc[m][n], 0, 0, 0);
#pragma unroll
    for (int m = 0; m < 4; ++m)
#pragma unroll
      for (int n = 0; n < 4; ++n)
        acc[m][n] = __builtin_amdgcn_mfma_f32_16x16x32_bf16(ah[m], bl[n], acc[m][n], 0, 0, 0);
    __syncthreads();
  }

  const bool isG = (cBase < 1024);
#pragma unroll
  for (int m = 0; m < 4; ++m) {
#pragma unroll
    for (int n = 0; n < 4; ++n) {
      const int col = cBase + wc * 64 + n * 16 + lr;
      const size_t row0 = rBase + wr * 64 + m * 16 + (l >> 4) * 4;
#pragma unroll
      for (int i = 0; i < 4; ++i) {
        float v = acc[m][n][i];
        if (isG) {
          v += bg[col];
          v = 1.f / (1.f + expf(-v));
          G[(row0 + i) * 1024 + col] = v;
        } else {
          v += bi[col - 1024];
          P[(row0 + i) * 1024 + (col - 1024)] = v;
        }
      }
    }
  }
}

// ---------------- persistent recurrence kernel (champion) ----------------
// 256 WGs x 256 thr. group g = bid>>5 (batches 4g..4g+3), rank = bid&31
// (e-rows rank*32..+32). Wave kq = K-quarter, polls its 8 producers.
// h layout: [parity][group][batch(4)][1024] bf16 hi / lo.
__global__ __launch_bounds__(256) void recur_kernel(
    const float* __restrict__ Ws, const float* __restrict__ bs,
    const float* __restrict__ G, float* out,
    unsigned short* h_hi, unsigned short* h_lo, int* flags) {
  __shared__ float part[2 * 4 * 4 * 32];  // [parity][kq][batch][32 e]
  const int g = blockIdx.x >> 5;
  const int rank = blockIdx.x & 31;
  const int tid = threadIdx.x;
  const int kq = tid >> 6, l = tid & 63;
  const int lr = l & 15, lh4 = l >> 4;

  // ---- Ws fragments -> registers (rank's 32 rows, wave's K-quarter) ----
  s16x8 bhi[2][8], blo[2][8];
#pragma unroll
  for (int nt = 0; nt < 2; ++nt) {
#pragma unroll
    for (int c = 0; c < 8; ++c) {
      const int e = rank * 32 + nt * 16 + lr;
      const int k = kq * 256 + c * 32 + lh4 * 8;
      const float* src = Ws + (size_t)e * DIM + k;
      f32x4 v0 = *(const f32x4*)src;
      f32x4 v1 = *(const f32x4*)(src + 4);
      s16x8 vh, vl;
#pragma unroll
      for (int j = 0; j < 4; ++j) {
        unsigned short hb = f2bf(v0[j]);
        vh[j] = (short)hb;
        vl[j] = (short)f2bf(v0[j] - bf2f(hb));
        unsigned short hb2 = f2bf(v1[j]);
        vh[4 + j] = (short)hb2;
        vl[4 + j] = (short)f2bf(v1[j] - bf2f(hb2));
      }
      bhi[nt][c] = vh; blo[nt][c] = vl;
    }
  }

  // ---- wave0 epilogue state: lane handles (batch=lh4, e=egl..egl+1) ----
  float hold0 = 0.f, hold1 = 0.f;
  float2 bs2 = {0.f, 0.f};
  size_t gpi = 0;
  int bgl = 0, egl = 0;
  if (tid < 64) {
    bgl = g * 4 + lh4;
    egl = rank * 32 + lr * 2;
    bs2 = *(const float2*)&bs[egl];
    gpi = ((size_t)bgl * SEQ) * DIM + egl;
  }
  float2 gA = {0, 0}, pA = {0, 0}, gB = {0, 0}, pB = {0, 0};
  if (tid < 64) { gA = *(const float2*)&G[gpi]; pA = *(const float2*)&out[gpi]; }

  // per-lane h-load base (element units); batch row = lr (<4 valid)
  const int lane_off = lr * 1024 + kq * 256 + lh4 * 8;
  const int* fp = flags + ((g << 5) + (kq << 3) + (l & 7)) * 16;
  int* myflag = flags + ((g << 5) + rank) * 16;

  auto body = [&](int t, float2& gc, float2& pc, float2& gn, float2& pn) {
    // ---- poll own 8 producers (>= t) ----
    {
      int v;
      do { v = cload4(fp); } while (__any(v < t));
    }
    __builtin_amdgcn_sched_barrier(0);

    // ---- load h_t fragments (sc1, coalesced) ----
    const unsigned short* Hh =
        h_hi + (size_t)(((t & 1) * 8 + g) * 4) * 1024 + lane_off;
    const unsigned short* Hl =
        h_lo + (size_t)(((t & 1) * 8 + g) * 4) * 1024 + lane_off;
    s16x8 ah[8], al[8];
    if (lr < 4) {
      HL8(ah, Hh);
      HL8(al, Hl);
    } else {
      s16x8 z8 = {0, 0, 0, 0, 0, 0, 0, 0};
#pragma unroll
      for (int c = 0; c < 8; ++c) { ah[c] = z8; al[c] = z8; }
    }
    asm volatile("s_waitcnt vmcnt(0)" ::: "memory");
    __builtin_amdgcn_sched_barrier(0);

    // ---- prefetch g,p for t+1 (plain cached loads; resolve during MFMA) ----
    if (tid < 64) {
      const size_t gpn = gpi + ((t + 1 < SEQ) ? DIM : 0);
      gn = *(const float2*)&G[gpn];
      pn = *(const float2*)&out[gpn];
    }

    // ---- 3-term split-bf16 MFMA (A rows = batches, 4 valid) ----
    f32x4 z = {0.f, 0.f, 0.f, 0.f};
    f32x4 aA[2], aB[2], aC[2];
#pragma unroll
    for (int nt = 0; nt < 2; ++nt) { aA[nt] = z; aB[nt] = z; aC[nt] = z; }
#pragma unroll
    for (int c = 0; c < 8; ++c) {
#pragma unroll
      for (int nt = 0; nt < 2; ++nt) {
        aA[nt] = __builtin_amdgcn_mfma_f32_16x16x32_bf16(ah[c], bhi[nt][c], aA[nt], 0, 0, 0);
        aB[nt] = __builtin_amdgcn_mfma_f32_16x16x32_bf16(al[c], bhi[nt][c], aB[nt], 0, 0, 0);
        aC[nt] = __builtin_amdgcn_mfma_f32_16x16x32_bf16(ah[c], blo[nt][c], aC[nt], 0, 0, 0);
      }
    }

    // ---- partials to LDS (valid batches: lanes lh4==0, regs i=0..3) ----
    if (lh4 == 0) {
#pragma unroll
      for (int nt = 0; nt < 2; ++nt) {
        f32x4 v = aA[nt] + aB[nt] + aC[nt];
#pragma unroll
        for (int i = 0; i < 4; ++i)
          part[(t & 1) * 512 + kq * 128 + i * 32 + nt * 16 + lr] = v[i];
      }
    }
    asm volatile("s_waitcnt lgkmcnt(0)" ::: "memory");
    __builtin_amdgcn_s_barrier();
    __builtin_amdgcn_sched_barrier(0);

    // ---- wave0: K-reduce + epilogue + publish ----
    if (tid < 64) {
      const int b = lh4, e2 = lr * 2;
      const float* pp = &part[(t & 1) * 512 + b * 32 + e2];
      float2 r0 = *(const float2*)&pp[0];
      float2 r1 = *(const float2*)&pp[128];
      float2 r2 = *(const float2*)&pp[256];
      float2 r3 = *(const float2*)&pp[384];
      const float s0 = r0.x + r1.x + r2.x + r3.x;
      const float s1 = r0.y + r1.y + r2.y + r3.y;
      const float mix0 = s0 + bs2.x + pc.x;
      const float mix1 = s1 + bs2.y + pc.y;
      const float h0 = gc.x * mix0 + (1.f - gc.x) * hold0;
      const float h1 = gc.y * mix1 + (1.f - gc.y) * hold1;
      hold0 = h0; hold1 = h1;

      const unsigned short hb0 = f2bf(h0), hb1 = f2bf(h1);
      const unsigned short lb0 = f2bf(h0 - bf2f(hb0)), lb1 = f2bf(h1 - bf2f(hb1));
      const size_t hoff =
          (size_t)((((t + 1) & 1) * 8 + g) * 4 + b) * 1024 + egl;
      cstore4u(h_hi + hoff, (unsigned)hb0 | ((unsigned)hb1 << 16));
      cstore4u(h_lo + hoff, (unsigned)lb0 | ((unsigned)lb1 << 16));
      asm volatile("s_waitcnt vmcnt(0)" ::: "memory");  // h visible before flag
      if (l == 0 && t < SEQ - 1) cstore4(myflag, t + 1);

      float2 ev; ev.x = h0; ev.y = h1;
      *(float2*)&out[gpi] = ev;  // emitted (overwrites consumed P slot)
      if (t == SEQ - 1)
        *(float2*)&out[BSD + (size_t)bgl * DIM + egl] = ev;
      gpi += ((t + 1 < SEQ) ? DIM : 0);
    }
  };

#pragma unroll 1
  for (int t = 0; t < SEQ; t += 2) {
    body(t, gA, pA, gB, pB);
    body(t + 1, gB, pB, gA, pA);
  }
}

// ---------------- launch ----------------
extern "C" void kernel_launch(void* const* d_in, const int* in_sizes, int n_in,
                              void* d_out, int out_size, void* d_ws, size_t ws_size,
                              hipStream_t stream) {
  (void)in_sizes; (void)n_in; (void)out_size; (void)ws_size;
  const float* x  = (const float*)d_in[0];
  const float* Wg = (const float*)d_in[1];
  const float* bg = (const float*)d_in[2];
  const float* Ws = (const float*)d_in[3];
  const float* bs = (const float*)d_in[4];
  const float* Wi = (const float*)d_in[5];
  const float* bi = (const float*)d_in[6];
  float* out = (float*)d_out;
  char* ws = (char*)d_ws;

  unsigned short* xh   = (unsigned short*)(ws);              // 64 MB
  unsigned short* xl   = (unsigned short*)(ws + 67108864);   // 64 MB
  unsigned short* wh   = (unsigned short*)(ws + 134217728);  // 4 MB (dead after gemm)
  unsigned short* wl   = (unsigned short*)(ws + 138412032);  // 4 MB (dead after gemm)
  float*          G    = (float*)(ws + 142606336);           // 128 MB
  unsigned short* h_hi = (unsigned short*)(ws + 276824064);  // 128 KB [2][8][4][1024]
  unsigned short* h_lo = (unsigned short*)(ws + 276955136);  // 128 KB
  int*            flags= (int*)(ws + 134217728);             // 16 KB (overlaps wh; init AFTER gemm)

  hipLaunchKernelGGL(split_x_kernel, dim3(4096), dim3(256), 0, stream,
                     x, xh, xl, (long)(BSD / 4));
  hipLaunchKernelGGL(split_w_kernel, dim3(2048), dim3(256), 0, stream, Wg, Wi, wh, wl);
  hipLaunchKernelGGL(gemm_gp_kernel, dim3(256, 16), dim3(256), 0, stream,
                     xh, xl, wh, wl, bg, bi, G, out);
  hipLaunchKernelGGL(init_kernel, dim3(64), dim3(256), 0, stream, h_hi, h_lo, flags);
  hipLaunchKernelGGL(recur_kernel, dim3(256), dim3(256), 0, stream,
                     Ws, bs, G, out, h_hi, h_lo, flags);
}